// Round 2
// baseline (732.627 us; speedup 1.0000x reference)
//
#include <hip/hip_runtime.h>

// ---------------------------------------------------------------------------
// Fused distance-weighted tanh attention (B=16, L=2048, D=128), MI355X gfx950.
//
// prep   : fp16 casts + transposes so all later LDS staging is linear.
// phase1 : q2w = dw@q2, k2w = dw@k2  (fp16x2 split, 3-product MFMA ~ fp32 acc)
// phase2 : S = (q/T)@k^T + (q2w/T)@k2w^T -> tanh -> mask -> attn store
//          out += P@v  (flash-style, no softmax so no rescale needed)
//
// Precision: distance scores sigma~676, tanh transition needs |dS|<~0.03 ->
// fp16x2 (hi+lo) on dw,q2,k2,q2w,k2w gives ~1e-3 score error. qk and PV
// terms are O(1)-scale -> single fp16 suffices.
// ---------------------------------------------------------------------------

#define NB 16
#define NL 2048
#define ND 128
#define NQD ((size_t)NB * NL * ND)  // 4,194,304 elements

typedef _Float16 f16;
typedef _Float16 f16x4 __attribute__((ext_vector_type(4)));
typedef _Float16 f16x8 __attribute__((ext_vector_type(8)));
typedef float f32x4 __attribute__((ext_vector_type(4)));

static constexpr float INV_T = 0.08838834764831845f;  // 1/sqrt(128)

__device__ __forceinline__ f32x4 mfma16(f16x8 a, f16x8 b, f32x4 c) {
  return __builtin_amdgcn_mfma_f32_16x16x32_f16(a, b, c, 0, 0, 0);
}

__device__ __forceinline__ float fast_tanh(float x) {
  float e = __expf(2.0f * x);                 // inf for big x -> tanh = 1
  return 1.0f - __fdividef(2.0f, e + 1.0f);   // x<<0: e->0 -> -1
}

// ---------------------------------------------------------------------------
// prep: qh = fp16(q/T) [b][l][d]; kh = fp16(k); vTh = fp16(v)^T [b][d][l];
//       q2Th/q2Tl, k2Th/k2Tl = fp16-split of q2^T, k2^T [b][d][l]
// ---------------------------------------------------------------------------
__global__ __launch_bounds__(256) void prep_kernel(
    const float* __restrict__ q, const float* __restrict__ k,
    const float* __restrict__ v, const float* __restrict__ q2,
    const float* __restrict__ k2,
    f16* __restrict__ qh, f16* __restrict__ kh, f16* __restrict__ vTh,
    f16* __restrict__ q2Th, f16* __restrict__ q2Tl,
    f16* __restrict__ k2Th, f16* __restrict__ k2Tl) {
  __shared__ float tile[32][33];
  const int b = blockIdx.z;
  const int l0 = blockIdx.y * 32;
  const int d0 = blockIdx.x * 32;
  const int tid = threadIdx.x;
  const int r = tid >> 3;
  const int c = (tid & 7) * 4;

  const size_t ebase = ((size_t)b * NL + (l0 + r)) * ND + d0 + c;
  {
    float4 x = *(const float4*)(q + ebase);
    f16x4 h = {(f16)(x.x * INV_T), (f16)(x.y * INV_T),
               (f16)(x.z * INV_T), (f16)(x.w * INV_T)};
    *(f16x4*)(qh + ebase) = h;
  }
  {
    float4 x = *(const float4*)(k + ebase);
    f16x4 h = {(f16)x.x, (f16)x.y, (f16)x.z, (f16)x.w};
    *(f16x4*)(kh + ebase) = h;
  }
  const size_t tbase = ((size_t)b * ND + (d0 + r)) * NL + l0 + c;
  {  // v transpose
    float4 x = *(const float4*)(v + ebase);
    tile[r][c] = x.x; tile[r][c + 1] = x.y; tile[r][c + 2] = x.z; tile[r][c + 3] = x.w;
    __syncthreads();
    f16x4 h = {(f16)tile[c][r], (f16)tile[c + 1][r],
               (f16)tile[c + 2][r], (f16)tile[c + 3][r]};
    *(f16x4*)(vTh + tbase) = h;
    __syncthreads();
  }
  {  // q2 transpose + split
    float4 x = *(const float4*)(q2 + ebase);
    tile[r][c] = x.x; tile[r][c + 1] = x.y; tile[r][c + 2] = x.z; tile[r][c + 3] = x.w;
    __syncthreads();
    float a0 = tile[c][r], a1 = tile[c + 1][r], a2 = tile[c + 2][r], a3 = tile[c + 3][r];
    f16 h0 = (f16)a0, h1 = (f16)a1, h2 = (f16)a2, h3 = (f16)a3;
    f16x4 hh = {h0, h1, h2, h3};
    f16x4 ll = {(f16)(a0 - (float)h0), (f16)(a1 - (float)h1),
                (f16)(a2 - (float)h2), (f16)(a3 - (float)h3)};
    *(f16x4*)(q2Th + tbase) = hh;
    *(f16x4*)(q2Tl + tbase) = ll;
    __syncthreads();
  }
  {  // k2 transpose + split
    float4 x = *(const float4*)(k2 + ebase);
    tile[r][c] = x.x; tile[r][c + 1] = x.y; tile[r][c + 2] = x.z; tile[r][c + 3] = x.w;
    __syncthreads();
    float a0 = tile[c][r], a1 = tile[c + 1][r], a2 = tile[c + 2][r], a3 = tile[c + 3][r];
    f16 h0 = (f16)a0, h1 = (f16)a1, h2 = (f16)a2, h3 = (f16)a3;
    f16x4 hh = {h0, h1, h2, h3};
    f16x4 ll = {(f16)(a0 - (float)h0), (f16)(a1 - (float)h1),
                (f16)(a2 - (float)h2), (f16)(a3 - (float)h3)};
    *(f16x4*)(k2Th + tbase) = hh;
    *(f16x4*)(k2Tl + tbase) = ll;
  }
}

// ---------------------------------------------------------------------------
// phase1: per block: 128 q-rows x (128 d of q2w ++ 128 d of k2w), K=2048.
// A = dw (fp32 -> hi/lo split at staging), B = pre-split q2T/k2T limbs.
// 3-product MFMA (hh, hl, lh). Epilogue: store split(q2w/T), split(k2w).
// LDS 96 KB. 8 waves: (wr 0..1) x (wn 0..3 over the 256-wide concat).
// ---------------------------------------------------------------------------
__global__ __launch_bounds__(512, 2) void phase1_kernel(
    const float* __restrict__ dw,
    const f16* __restrict__ q2Th, const f16* __restrict__ q2Tl,
    const f16* __restrict__ k2Th, const f16* __restrict__ k2Tl,
    f16* __restrict__ q2w_h, f16* __restrict__ q2w_l,
    f16* __restrict__ k2w_h, f16* __restrict__ k2w_l) {
  extern __shared__ f16 lds[];
  f16* Ah = lds;             // [128][64] swz (r&7)<<3
  f16* Al = lds + 8192;
  f16* Bqh = lds + 16384;    // [128 d][64 l]
  f16* Bql = lds + 24576;
  f16* Bkh = lds + 32768;
  f16* Bkl = lds + 40960;

  const int P = blockIdx.x;
  const int Lg = (P & 7) * 32 + (P >> 3);  // XCD-chunked remap (bijective)
  const int b = Lg >> 4, qt = Lg & 15;
  const int q0 = qt * 128;
  const int tid = threadIdx.x;
  const int lane = tid & 63, wid = tid >> 6;
  const int wr = wid >> 2, wn = wid & 3;

  f32x4 acc[4][4];
#pragma unroll
  for (int m = 0; m < 4; m++)
#pragma unroll
    for (int n = 0; n < 4; n++) acc[m][n] = (f32x4){0.f, 0.f, 0.f, 0.f};

  const size_t dwbase = (size_t)b * NL * NL + (size_t)q0 * NL;
  const size_t tq2 = (size_t)b * ND * NL;

  for (int kt = 0; kt < 32; ++kt) {
    const int l0 = kt * 64;
    // stage A (dw fp32 -> hi/lo)
#pragma unroll
    for (int i = 0; i < 4; i++) {
      int u = tid + i * 512;
      int r = u >> 4, c4 = (u & 15) * 4;
      float4 x = *(const float4*)(dw + dwbase + (size_t)r * NL + l0 + c4);
      f16 h0 = (f16)x.x, h1 = (f16)x.y, h2 = (f16)x.z, h3 = (f16)x.w;
      f16x4 hh = {h0, h1, h2, h3};
      f16x4 ll = {(f16)(x.x - (float)h0), (f16)(x.y - (float)h1),
                  (f16)(x.z - (float)h2), (f16)(x.w - (float)h3)};
      int cs = c4 ^ ((r & 7) << 3);
      *(f16x4*)(Ah + r * 64 + cs) = hh;
      *(f16x4*)(Al + r * 64 + cs) = ll;
    }
    // stage B (already split limbs, linear copy)
#pragma unroll
    for (int i = 0; i < 8; i++) {
      int u = tid + i * 512;
      int arr = u >> 10, w = u & 1023;
      int r = w >> 3, c8 = (w & 7) * 8;
      const f16* src = (arr == 0) ? q2Th : (arr == 1) ? q2Tl : (arr == 2) ? k2Th : k2Tl;
      f16x8 x = *(const f16x8*)(src + tq2 + (size_t)r * NL + l0 + c8);
      f16* dst = (arr == 0) ? Bqh : (arr == 1) ? Bql : (arr == 2) ? Bkh : Bkl;
      *(f16x8*)(dst + r * 64 + (c8 ^ ((r & 7) << 3))) = x;
    }
    __syncthreads();
#pragma unroll
    for (int kk = 0; kk < 2; kk++) {
      const int kb = kk * 32 + (lane >> 4) * 8;
      f16x8 ah[4], al[4], bh[4], bl[4];
#pragma unroll
      for (int m = 0; m < 4; m++) {
        int rr = wr * 64 + m * 16 + (lane & 15);
        int off = rr * 64 + (kb ^ ((rr & 7) << 3));
        ah[m] = *(const f16x8*)(Ah + off);
        al[m] = *(const f16x8*)(Al + off);
      }
      const f16* Bh = (wn < 2) ? Bqh : Bkh;
      const f16* Bl = (wn < 2) ? Bql : Bkl;
      const int nbase = (wn & 1) * 64;
#pragma unroll
      for (int n = 0; n < 4; n++) {
        int rr = nbase + n * 16 + (lane & 15);
        int off = rr * 64 + (kb ^ ((rr & 7) << 3));
        bh[n] = *(const f16x8*)(Bh + off);
        bl[n] = *(const f16x8*)(Bl + off);
      }
#pragma unroll
      for (int m = 0; m < 4; m++)
#pragma unroll
        for (int n = 0; n < 4; n++) {
          acc[m][n] = mfma16(ah[m], bh[n], acc[m][n]);
          acc[m][n] = mfma16(ah[m], bl[n], acc[m][n]);
          acc[m][n] = mfma16(al[m], bh[n], acc[m][n]);
        }
    }
    __syncthreads();
  }
  // epilogue: split-store (q2w gets the 1/T scale folded in)
  const bool isQ = (wn < 2);
  f16* outH = isQ ? q2w_h : k2w_h;
  f16* outL = isQ ? q2w_l : k2w_l;
  const float sc = isQ ? INV_T : 1.0f;
#pragma unroll
  for (int m = 0; m < 4; m++)
#pragma unroll
    for (int n = 0; n < 4; n++)
#pragma unroll
      for (int i = 0; i < 4; i++) {
        int qrow = q0 + wr * 64 + m * 16 + (lane >> 4) * 4 + i;
        int dcol = (wn & 1) * 64 + n * 16 + (lane & 15);
        float vv = acc[m][n][i] * sc;
        f16 h = (f16)vv;
        f16 l = (f16)(vv - (float)h);
        size_t idx = ((size_t)b * NL + qrow) * ND + dcol;
        outH[idx] = h;
        outL[idx] = l;
      }
}

// ---------------------------------------------------------------------------
// phase2: per block: 128 q-rows, loop over 32 k-tiles of 64.
// S = qh@Kh^T + Q2h@K2h^T + Q2h@K2l^T + Q2l@K2h^T (fp32 acc, pre-scaled)
// -> tanh -> mask -> attn (fp32, nontemporal) -> P(fp16, LDS) -> out += P@V.
// LDS 160 KB exactly; P aliases Kh. 8 waves: (wq 0..3) x (wk 0..1).
// ---------------------------------------------------------------------------
__global__ __launch_bounds__(512, 2) void phase2_kernel(
    const f16* __restrict__ qh, const f16* __restrict__ kh,
    const f16* __restrict__ vTh,
    const f16* __restrict__ q2w_h, const f16* __restrict__ q2w_l,
    const f16* __restrict__ k2w_h, const f16* __restrict__ k2w_l,
    const int* __restrict__ lens,
    float* __restrict__ outp, float* __restrict__ attnp) {
  extern __shared__ f16 lds[];
  f16* Qh = lds;             // [128][128] swz (r&15)<<3
  f16* Q2h = lds + 16384;
  f16* Q2l = lds + 32768;
  f16* Kh = lds + 49152;     // [64][128]  swz (r&15)<<3
  f16* K2h = lds + 57344;
  f16* K2l = lds + 65536;
  f16* Vt = lds + 73728;     // [128 d][64 k] swz (r&7)<<3
  f16* Pl = Kh;              // alias: P [128 q][64 k] swz (r&7)<<3

  const int P = blockIdx.x;
  const int Lg = (P & 7) * 32 + (P >> 3);
  const int b = Lg >> 4, qt = Lg & 15;
  const int q0 = qt * 128;
  const int tid = threadIdx.x, lane = tid & 63, wid = tid >> 6;
  const int wq = wid >> 1, wk = wid & 1;
  const int len = lens[b];

  // resident Q-side staging (linear copies of pre-converted arrays)
  const size_t qbase = ((size_t)b * NL + q0) * ND;
#pragma unroll
  for (int i = 0; i < 12; i++) {
    int u = tid + i * 512;
    int arr = u >> 11, w = u & 2047;
    int r = w >> 4, c8 = (w & 15) * 8;
    const f16* src = (arr == 0) ? qh : (arr == 1) ? q2w_h : q2w_l;
    f16x8 x = *(const f16x8*)(src + qbase + (size_t)r * ND + c8);
    f16* dst = (arr == 0) ? Qh : (arr == 1) ? Q2h : Q2l;
    *(f16x8*)(dst + r * 128 + (c8 ^ ((r & 15) << 3))) = x;
  }
  __syncthreads();

  f32x4 oacc[2][4];
#pragma unroll
  for (int m = 0; m < 2; m++)
#pragma unroll
    for (int n = 0; n < 4; n++) oacc[m][n] = (f32x4){0.f, 0.f, 0.f, 0.f};

  const size_t kbbase = (size_t)b * NL * ND;
  const size_t vtbase = (size_t)b * ND * NL;
  float* attnrow = attnp + ((size_t)b * NL + q0) * NL;

  for (int kt = 0; kt < 32; ++kt) {
    const int k0 = kt * 64;
    if (k0 >= len) {  // fully masked tile: just write zeros to attn
      f32x4 z = {0.f, 0.f, 0.f, 0.f};
#pragma unroll
      for (int i = 0; i < 4; i++) {
        int u = tid + i * 512;
        int r = u >> 4, c4 = (u & 15) * 4;
        __builtin_nontemporal_store(z, (f32x4*)(attnrow + (size_t)r * NL + k0 + c4));
      }
      continue;
    }
    // stage K-side
#pragma unroll
    for (int i = 0; i < 8; i++) {
      int u = tid + i * 512;
      int arr = u >> 10, w = u & 1023;
      if (arr < 3) {
        int r = w >> 4, c8 = (w & 15) * 8;
        const f16* src = (arr == 0) ? kh : (arr == 1) ? k2w_h : k2w_l;
        f16x8 x = *(const f16x8*)(src + kbbase + (size_t)(k0 + r) * ND + c8);
        f16* dst = (arr == 0) ? Kh : (arr == 1) ? K2h : K2l;
        *(f16x8*)(dst + r * 128 + (c8 ^ ((r & 15) << 3))) = x;
      } else {
        int r = w >> 3, c8 = (w & 7) * 8;
        f16x8 x = *(const f16x8*)(vTh + vtbase + (size_t)r * NL + k0 + c8);
        *(f16x8*)(Vt + r * 64 + (c8 ^ ((r & 7) << 3))) = x;
      }
    }
    __syncthreads();

    // S tile: wave computes 32q x 32k
    f32x4 s[2][2];
#pragma unroll
    for (int m = 0; m < 2; m++)
#pragma unroll
      for (int n = 0; n < 2; n++) s[m][n] = (f32x4){0.f, 0.f, 0.f, 0.f};
#pragma unroll
    for (int kk = 0; kk < 4; kk++) {
      const int kb = kk * 32 + (lane >> 4) * 8;
      f16x8 qa[2], a2h[2], a2l[2], kb_[2], b2h[2], b2l[2];
#pragma unroll
      for (int m = 0; m < 2; m++) {
        int rq = wq * 32 + m * 16 + (lane & 15);
        int off = rq * 128 + (kb ^ ((rq & 15) << 3));
        qa[m] = *(const f16x8*)(Qh + off);
        a2h[m] = *(const f16x8*)(Q2h + off);
        a2l[m] = *(const f16x8*)(Q2l + off);
      }
#pragma unroll
      for (int n = 0; n < 2; n++) {
        int rk = wk * 32 + n * 16 + (lane & 15);
        int off = rk * 128 + (kb ^ ((rk & 15) << 3));
        kb_[n] = *(const f16x8*)(Kh + off);
        b2h[n] = *(const f16x8*)(K2h + off);
        b2l[n] = *(const f16x8*)(K2l + off);
      }
#pragma unroll
      for (int m = 0; m < 2; m++)
#pragma unroll
        for (int n = 0; n < 2; n++) {
          s[m][n] = mfma16(qa[m], kb_[n], s[m][n]);
          s[m][n] = mfma16(a2h[m], b2h[n], s[m][n]);
          s[m][n] = mfma16(a2h[m], b2l[n], s[m][n]);
          s[m][n] = mfma16(a2l[m], b2h[n], s[m][n]);
        }
    }
    // tanh + mask + attn store
    float tv[2][2][4];
#pragma unroll
    for (int m = 0; m < 2; m++)
#pragma unroll
      for (int n = 0; n < 2; n++)
#pragma unroll
        for (int i = 0; i < 4; i++) {
          int qrow = wq * 32 + m * 16 + (lane >> 4) * 4 + i;
          int kcol = k0 + wk * 32 + n * 16 + (lane & 15);
          float t = (kcol < len) ? fast_tanh(s[m][n][i]) : 0.0f;
          tv[m][n][i] = t;
          __builtin_nontemporal_store(t, attnrow + (size_t)qrow * NL + kcol);
        }
    __syncthreads();  // all waves done reading Kh before P overwrites it
#pragma unroll
    for (int m = 0; m < 2; m++)
#pragma unroll
      for (int n = 0; n < 2; n++)
#pragma unroll
        for (int i = 0; i < 4; i++) {
          int rloc = wq * 32 + m * 16 + (lane >> 4) * 4 + i;
          int ccol = wk * 32 + n * 16 + (lane & 15);
          Pl[rloc * 64 + (ccol ^ ((rloc & 7) << 3))] = (f16)tv[m][n][i];
        }
    __syncthreads();
    // PV: wave computes 32q x 64d, K = 64
#pragma unroll
    for (int ks = 0; ks < 2; ks++) {
      const int kb2 = ks * 32 + (lane >> 4) * 8;
      f16x8 pa[2], vb[4];
#pragma unroll
      for (int m = 0; m < 2; m++) {
        int rq = wq * 32 + m * 16 + (lane & 15);
        pa[m] = *(const f16x8*)(Pl + rq * 64 + (kb2 ^ ((rq & 7) << 3)));
      }
#pragma unroll
      for (int n = 0; n < 4; n++) {
        int dr = wk * 64 + n * 16 + (lane & 15);
        vb[n] = *(const f16x8*)(Vt + dr * 64 + (kb2 ^ ((dr & 7) << 3)));
      }
#pragma unroll
      for (int m = 0; m < 2; m++)
#pragma unroll
        for (int n = 0; n < 4; n++) oacc[m][n] = mfma16(pa[m], vb[n], oacc[m][n]);
    }
    __syncthreads();  // PV reads done before next stage overwrites Kh(P)/Vt
  }
  // out store
#pragma unroll
  for (int m = 0; m < 2; m++)
#pragma unroll
    for (int n = 0; n < 4; n++)
#pragma unroll
      for (int i = 0; i < 4; i++) {
        int qrow = q0 + wq * 32 + m * 16 + (lane >> 4) * 4 + i;
        int dcol = wk * 64 + n * 16 + (lane & 15);
        outp[((size_t)b * NL + qrow) * ND + dcol] = oacc[m][n][i];
      }
}

// ---------------------------------------------------------------------------
extern "C" void kernel_launch(void* const* d_in, const int* in_sizes, int n_in,
                              void* d_out, int out_size, void* d_ws, size_t ws_size,
                              hipStream_t stream) {
  (void)in_sizes; (void)n_in; (void)out_size; (void)ws_size;
  const float* q = (const float*)d_in[0];
  const float* k = (const float*)d_in[1];
  const float* v = (const float*)d_in[2];
  const float* q2 = (const float*)d_in[3];
  const float* k2 = (const float*)d_in[4];
  const float* dw = (const float*)d_in[5];
  const int* lens = (const int*)d_in[6];

  // workspace carve: 11 half-arrays of 4,194,304 elements = 92.3 MB total
  f16* q2w_h = (f16*)d_ws;
  f16* q2w_l = q2w_h + NQD;
  f16* k2w_h = q2w_l + NQD;
  f16* k2w_l = k2w_h + NQD;
  f16* qh = k2w_l + NQD;
  f16* kh = qh + NQD;
  f16* vTh = kh + NQD;
  f16* q2Th = vTh + NQD;
  f16* q2Tl = q2Th + NQD;
  f16* k2Th = q2Tl + NQD;
  f16* k2Tl = k2Th + NQD;

  float* outp = (float*)d_out;
  float* attnp = outp + NQD;  // outputs concatenated: output, then attn

  (void)hipFuncSetAttribute(reinterpret_cast<const void*>(phase1_kernel),
                            hipFuncAttributeMaxDynamicSharedMemorySize, 98304);
  (void)hipFuncSetAttribute(reinterpret_cast<const void*>(phase2_kernel),
                            hipFuncAttributeMaxDynamicSharedMemorySize, 163840);

  prep_kernel<<<dim3(4, 64, 16), 256, 0, stream>>>(
      q, k, v, q2, k2, qh, kh, vTh, q2Th, q2Tl, k2Th, k2Tl);
  phase1_kernel<<<256, 512, 98304, stream>>>(
      dw, q2Th, q2Tl, k2Th, k2Tl, q2w_h, q2w_l, k2w_h, k2w_l);
  phase2_kernel<<<256, 512, 163840, stream>>>(
      qh, kh, vTh, q2w_h, q2w_l, k2w_h, k2w_l, lens, outp, attnp);
}